// Round 3
// baseline (39002.368 us; speedup 1.0000x reference)
//
#include <hip/hip_runtime.h>

#define T_LEN 2048
#define G_N   24
#define V_N   2048
#define K_N   512

// ---- rnn_single weight tiers (32 chunks of 4 k-rows per 128-row quarter) ----
// chunks [0,NREGC)        -> registers   (24 rows, 96 VGPR/thread)
// chunks [NREGC,SCH0)     -> LDS         (16 rows, 128 KB)
// chunks [SCH0,32)        -> streamed from L2 every step through a 4-chunk
//                            sliding window (float4 stg[4][4] = 64 VGPR, all
//                            indices compile-time after full unroll)
// R2 lesson: __launch_bounds__(512,2) makes LLVM cap VGPRs at 128 (budget/2)
// -> ~90 regs spilled to scratch -> 15us/step latency-bound. (512,1) caps at
// 256; demand here ~200 -> no spill. VGPR_Count>128 is the verification.
#define NREGC 6
#define NLDSC 4
#define SCH0  (NREGC + NLDSC)   // 10
#define NCHUNK 32
#define LOOK 4

// ---------------- workspace layout (bytes) ----------------
#define TOK_OFF    4096
#define ROWS_OFF   16384
#define P_OFF      524288

// ---- phase 0: recover tokens from one-hot rows (exactly one 1.0 per row) ----
__global__ void tok_kernel(const float* __restrict__ seq, int* __restrict__ tokens) {
    int wid  = (blockIdx.x * blockDim.x + threadIdx.x) >> 6;   // one wave per row t
    int lane = threadIdx.x & 63;
    if (wid >= T_LEN) return;
    const float* row = seq + (size_t)wid * V_N;
    for (int i = lane; i < V_N; i += 64) {
        if (row[i] > 0.5f) tokens[wid] = i;   // exactly one lane hits: race-free
    }
}

// ---- phase 1: rows[g][t] = perms[g][token[t]] ----
__global__ void rows_kernel(const int* __restrict__ tokens, const int* __restrict__ perms,
                            int* __restrict__ rows) {
    int idx = blockIdx.x * blockDim.x + threadIdx.x;   // g*T + t
    if (idx >= G_N * T_LEN) return;
    int g = idx / T_LEN, t = idx - g * T_LEN;
    rows[idx] = perms[g * V_N + tokens[t]];
}

// ---- phase 2: P = W_e @ Wx + b  (2048x512 @ 512x512, f32 vector GEMM) ----
__global__ __launch_bounds__(256) void pgemm_kernel(const float* __restrict__ We,
                                                    const float* __restrict__ Wx,
                                                    const float* __restrict__ b,
                                                    float* __restrict__ P) {
    __shared__ float As[16][72];   // [k][v], padded
    __shared__ float Bs[16][68];   // [k][j], padded (68 keeps float4 alignment)
    int tid = threadIdx.x;
    int bx = blockIdx.x & 7;        // j tile (K_N/64 = 8)
    int by = blockIdx.x >> 3;       // v tile (V_N/64 = 32)
    int tx = tid & 15, ty = tid >> 4;
    int v0 = by * 64, j0 = bx * 64;
    float acc[4][4] = {};
    for (int k0 = 0; k0 < K_N; k0 += 16) {
        int ar = tid >> 2;            // 0..63
        int ac = (tid & 3) << 2;      // 0,4,8,12
        float4 av = *(const float4*)(We + (size_t)(v0 + ar) * K_N + k0 + ac);
        As[ac + 0][ar] = av.x; As[ac + 1][ar] = av.y;
        As[ac + 2][ar] = av.z; As[ac + 3][ar] = av.w;
        int br = tid >> 4;            // 0..15
        int bc = (tid & 15) << 2;     // 0..60
        float4 bv = *(const float4*)(Wx + (size_t)(k0 + br) * K_N + j0 + bc);
        *(float4*)&Bs[br][bc] = bv;
        __syncthreads();
#pragma unroll
        for (int kk = 0; kk < 16; kk++) {
            float a0 = As[kk][ty * 4 + 0], a1 = As[kk][ty * 4 + 1];
            float a2 = As[kk][ty * 4 + 2], a3 = As[kk][ty * 4 + 3];
            float4 bb = *(const float4*)&Bs[kk][tx * 4];
            acc[0][0] += a0 * bb.x; acc[0][1] += a0 * bb.y; acc[0][2] += a0 * bb.z; acc[0][3] += a0 * bb.w;
            acc[1][0] += a1 * bb.x; acc[1][1] += a1 * bb.y; acc[1][2] += a1 * bb.z; acc[1][3] += a1 * bb.w;
            acc[2][0] += a2 * bb.x; acc[2][1] += a2 * bb.y; acc[2][2] += a2 * bb.z; acc[2][3] += a2 * bb.w;
            acc[3][0] += a3 * bb.x; acc[3][1] += a3 * bb.y; acc[3][2] += a3 * bb.z; acc[3][3] += a3 * bb.w;
        }
        __syncthreads();
    }
    float4 bb = *(const float4*)(b + j0 + tx * 4);
#pragma unroll
    for (int i = 0; i < 4; i++) {
        float4 r;
        r.x = acc[i][0] + bb.x; r.y = acc[i][1] + bb.y;
        r.z = acc[i][2] + bb.z; r.w = acc[i][3] + bb.w;
        *(float4*)(P + (size_t)(v0 + ty * 4 + i) * K_N + j0 + tx * 4) = r;
    }
}

// ---- phase 3: single-workgroup-per-chain RNN (NO inter-WG sync) ----
// 48 blocks x 512 threads; block = (g, dir). Thread (q = tid>>7, c = tid&127)
// owns columns {4c..4c+3} over k-quarter [128q, 128q+128). Per k-row one
// float4 of Wh gives the 4 columns' weights -> all weight traffic (reg fill,
// LDS fill, per-step L2 stream) is coalesced dwordx4 from row-major Wh.
// Numerics identical to the passing kernels: mod-4 accumulators per column,
// (A+B)+(C+D), quarters reduced p0+p1+p2+p3, z = xv+sum, clamp +-15,
// tanh via __expf(2z).
__global__ __launch_bounds__(512, 1) void rnn_single(
    const float* __restrict__ P, const float* __restrict__ Wh,
    const int* __restrict__ rows, float* __restrict__ out) {

    __shared__ __align__(16) float  lds_h[K_N];                  // 2 KB
    __shared__ __align__(16) float4 Wlds4[NLDSC * 4 * 512];      // 128 KB: [row][tid]
    __shared__ __align__(16) float4 partial4[4 * 128];           // 8 KB: [q][c]

    const int tid = threadIdx.x;
    const int q   = tid >> 7;          // k-quarter
    const int c   = tid & 127;         // column group (cols 4c..4c+3)
    const int kb  = q << 7;            // k base
    const int g   = blockIdx.x >> 1;
    const int dir = blockIdx.x & 1;

    const float4* __restrict__ Wh4 = (const float4*)Wh;
    const float4* __restrict__ wbase = Wh4 + (size_t)kb * 128 + c;  // row stride 128 f4

    // one-time register tier fill (coalesced)
    float4 Wreg[NREGC * 4];
#pragma unroll
    for (int kk = 0; kk < NREGC * 4; kk++)
        Wreg[kk] = wbase[(size_t)kk * 128];
    // one-time LDS tier fill (each thread writes/reads only its own slots)
#pragma unroll
    for (int r = 0; r < NLDSC * 4; r++)
        Wlds4[r * 512 + tid] = wbase[(size_t)(NREGC * 4 + r) * 128];

    lds_h[tid] = 0.f;

    const int* __restrict__ myrows = rows + g * T_LEN;
    // x prefetch for s=0; row prefetch for s=1
    int t0 = (dir == 0) ? 0 : (T_LEN - 2);
    float xv = P[(size_t)myrows[t0] * K_N + tid];
    int t1 = (dir == 0) ? 1 : (T_LEN - 3);
    int rnxt = myrows[t1];

    const size_t outbase = (size_t)g * 1024 + (size_t)dir * 512 + tid;
    float h_prev = 0.f;
    size_t prev_addr = 0;

    __syncthreads();

    for (int s = 0; s < T_LEN; s++) {
        // staggered out-store of previous step's h: off the critical path
        if (s > 0) __builtin_nontemporal_store(h_prev, &out[prev_addr]);
        // prefetch x for s+1 (row preloaded), and row index for s+2
        float xv_next = 0.f;
        if (s + 1 < T_LEN)
            xv_next = P[(size_t)rnxt * K_N + tid];
        if (s + 2 < T_LEN) {
            int sn = s + 2;
            int tn = (dir == 0) ? sn : ((sn == T_LEN - 1) ? (T_LEN - 1) : (T_LEN - 2 - sn));
            rnxt = myrows[tn];
        }

        const float4* __restrict__ h4 = (const float4*)(lds_h + kb);  // wave-uniform
        float4 accA = {0,0,0,0}, accB = {0,0,0,0}, accC = {0,0,0,0}, accD = {0,0,0,0};
        float4 stg[LOOK][4];   // 16 float4 sliding window; i&3 compile-time after unroll

        // stream prologue: LOOK chunks in flight before first streamed use;
        // latency hides under the register/LDS-tier chunks 0..9.
#pragma unroll
        for (int i = SCH0; i < SCH0 + LOOK; i++) {
#pragma unroll
            for (int e = 0; e < 4; e++)
                stg[i & (LOOK - 1)][e] = wbase[(size_t)(4 * i + e) * 128];
        }
#pragma unroll
        for (int i = 0; i < NCHUNK; i++) {
            float4 hv = h4[i];   // uniform address -> LDS broadcast, conflict-free
            float4 w0, w1, w2, w3;
            if (i < NREGC) {                   // register tier
                w0 = Wreg[4 * i + 0]; w1 = Wreg[4 * i + 1];
                w2 = Wreg[4 * i + 2]; w3 = Wreg[4 * i + 3];
            } else if (i < SCH0) {             // LDS tier (own slots, no conflict)
                int r = (i - NREGC) * 4;
                w0 = Wlds4[(r + 0) * 512 + tid]; w1 = Wlds4[(r + 1) * 512 + tid];
                w2 = Wlds4[(r + 2) * 512 + tid]; w3 = Wlds4[(r + 3) * 512 + tid];
            } else {                           // streamed tier
                w0 = stg[i & (LOOK - 1)][0]; w1 = stg[i & (LOOK - 1)][1];
                w2 = stg[i & (LOOK - 1)][2]; w3 = stg[i & (LOOK - 1)][3];
            }
            accA.x += hv.x * w0.x; accA.y += hv.x * w0.y; accA.z += hv.x * w0.z; accA.w += hv.x * w0.w;
            accB.x += hv.y * w1.x; accB.y += hv.y * w1.y; accB.z += hv.y * w1.z; accB.w += hv.y * w1.w;
            accC.x += hv.z * w2.x; accC.y += hv.z * w2.y; accC.z += hv.z * w2.z; accC.w += hv.z * w2.w;
            accD.x += hv.w * w3.x; accD.y += hv.w * w3.y; accD.z += hv.w * w3.z; accD.w += hv.w * w3.w;
            // refill this window slot with chunk i+LOOK (steady-state stream)
            if (i >= SCH0 && i + LOOK < NCHUNK) {
#pragma unroll
                for (int e = 0; e < 4; e++)
                    stg[i & (LOOK - 1)][e] = wbase[(size_t)(4 * (i + LOOK) + e) * 128];
            }
        }
        float4 res;
        res.x = (accA.x + accB.x) + (accC.x + accD.x);
        res.y = (accA.y + accB.y) + (accC.y + accD.y);
        res.z = (accA.z + accB.z) + (accC.z + accD.z);
        res.w = (accA.w + accB.w) + (accC.w + accD.w);
        partial4[(q << 7) + c] = res;      // 16B/lane, consecutive -> conflict-free
        __syncthreads();                   // A

        // reduce: thread tid owns column j = tid
        const float* pf = (const float*)partial4;
        float p0 = pf[0 * 512 + tid], p1 = pf[1 * 512 + tid];
        float p2 = pf[2 * 512 + tid], p3 = pf[3 * 512 + tid];
        float sum = p0 + p1 + p2 + p3;
        float z = xv + sum;
        z = fminf(15.f, fmaxf(-15.f, z));
        float e2 = __expf(2.f * z);
        float h1 = 1.f - 2.f / (e2 + 1.f);                 // tanh(z)
        xv = xv_next;

        int tphys = (dir == 0) ? s : ((s == T_LEN - 1) ? (T_LEN - 1) : (T_LEN - 2 - s));
        prev_addr = (size_t)tphys * (G_N * 1024) + outbase;
        h_prev = h1;
        if (s == T_LEN - 1) break;
        lds_h[tid] = h1;                   // old h fully consumed before barrier A
        __syncthreads();                   // B: h_s visible for next step
    }
    __builtin_nontemporal_store(h_prev, &out[prev_addr]);
    __builtin_nontemporal_store(h_prev, &out[(size_t)T_LEN * (G_N * 1024) + outbase]);
}

extern "C" void kernel_launch(void* const* d_in, const int* in_sizes, int n_in,
                              void* d_out, int out_size, void* d_ws, size_t ws_size,
                              hipStream_t stream) {
    const float* seq   = (const float*)d_in[0];
    const int*   perms = (const int*)d_in[1];
    const float* We    = (const float*)d_in[2];
    const float* Wx    = (const float*)d_in[3];
    const float* Wh    = (const float*)d_in[4];
    const float* b     = (const float*)d_in[5];
    float* out = (float*)d_out;
    char* ws = (char*)d_ws;

    int*   tokens = (int*)(ws + TOK_OFF);
    int*   rows   = (int*)(ws + ROWS_OFF);
    float* P      = (float*)(ws + P_OFF);

    tok_kernel<<<512, 256, 0, stream>>>(seq, tokens);
    rows_kernel<<<(G_N * T_LEN + 255) / 256, 256, 0, stream>>>(tokens, perms, rows);
    pgemm_kernel<<<256, 256, 0, stream>>>(We, Wx, b, P);
    rnn_single<<<G_N * 2, 512, 0, stream>>>(P, Wh, rows, out);
}

// Round 4
// 7134.278 us; speedup vs baseline: 5.4669x; 5.4669x over previous
//
#include <hip/hip_runtime.h>

#define T_LEN 2048
#define G_N   24
#define V_N   2048
#define K_N   512
#define NCL   48          // 24 groups x 2 directions
#define NBLK  96          // 2 workgroups (k-halves) per chain

// ---------------- workspace layout (bytes) ----------------
#define FLAGS_OFF  0
#define TOK_OFF    4096
#define ROWS_OFF   16384
#define HBUF_OFF   262144     // 48 cl x 2 ws x 2 bufs x 512 f32 = 384 KB
#define P_OFF      786432     // 4 MB

#define LOAD_RLX(p)     __hip_atomic_load((p), __ATOMIC_RELAXED, __HIP_MEMORY_SCOPE_AGENT)
#define STORE_RLX(p, v) __hip_atomic_store((p), (v), __ATOMIC_RELAXED, __HIP_MEMORY_SCOPE_AGENT)

// ---- phase 0: recover tokens from one-hot rows ----
__global__ void tok_kernel(const float* __restrict__ seq, int* __restrict__ tokens) {
    int wid  = (blockIdx.x * blockDim.x + threadIdx.x) >> 6;
    int lane = threadIdx.x & 63;
    if (wid >= T_LEN) return;
    const float* row = seq + (size_t)wid * V_N;
    for (int i = lane; i < V_N; i += 64) {
        if (row[i] > 0.5f) tokens[wid] = i;
    }
}

// ---- phase 1: rows[g][t] = perms[g][token[t]] ----
__global__ void rows_kernel(const int* __restrict__ tokens, const int* __restrict__ perms,
                            int* __restrict__ rows) {
    int idx = blockIdx.x * blockDim.x + threadIdx.x;
    if (idx >= G_N * T_LEN) return;
    int g = idx / T_LEN, t = idx - g * T_LEN;
    rows[idx] = perms[g * V_N + tokens[t]];
}

// ---- phase 2: P = W_e @ Wx + b ----
__global__ __launch_bounds__(256) void pgemm_kernel(const float* __restrict__ We,
                                                    const float* __restrict__ Wx,
                                                    const float* __restrict__ b,
                                                    float* __restrict__ P) {
    __shared__ float As[16][72];
    __shared__ float Bs[16][68];
    int tid = threadIdx.x;
    int bx = blockIdx.x & 7;
    int by = blockIdx.x >> 3;
    int tx = tid & 15, ty = tid >> 4;
    int v0 = by * 64, j0 = bx * 64;
    float acc[4][4] = {};
    for (int k0 = 0; k0 < K_N; k0 += 16) {
        int ar = tid >> 2;
        int ac = (tid & 3) << 2;
        float4 av = *(const float4*)(We + (size_t)(v0 + ar) * K_N + k0 + ac);
        As[ac + 0][ar] = av.x; As[ac + 1][ar] = av.y;
        As[ac + 2][ar] = av.z; As[ac + 3][ar] = av.w;
        int br = tid >> 4;
        int bc = (tid & 15) << 2;
        float4 bv = *(const float4*)(Wx + (size_t)(k0 + br) * K_N + j0 + bc);
        *(float4*)&Bs[br][bc] = bv;
        __syncthreads();
#pragma unroll
        for (int kk = 0; kk < 16; kk++) {
            float a0 = As[kk][ty * 4 + 0], a1 = As[kk][ty * 4 + 1];
            float a2 = As[kk][ty * 4 + 2], a3 = As[kk][ty * 4 + 3];
            float4 bb = *(const float4*)&Bs[kk][tx * 4];
            acc[0][0] += a0 * bb.x; acc[0][1] += a0 * bb.y; acc[0][2] += a0 * bb.z; acc[0][3] += a0 * bb.w;
            acc[1][0] += a1 * bb.x; acc[1][1] += a1 * bb.y; acc[1][2] += a1 * bb.z; acc[1][3] += a1 * bb.w;
            acc[2][0] += a2 * bb.x; acc[2][1] += a2 * bb.y; acc[2][2] += a2 * bb.z; acc[2][3] += a2 * bb.w;
            acc[3][0] += a3 * bb.x; acc[3][1] += a3 * bb.y; acc[3][2] += a3 * bb.z; acc[3][3] += a3 * bb.w;
        }
        __syncthreads();
    }
    float4 bb = *(const float4*)(b + j0 + tx * 4);
#pragma unroll
    for (int i = 0; i < 4; i++) {
        float4 r;
        r.x = acc[i][0] + bb.x; r.y = acc[i][1] + bb.y;
        r.z = acc[i][2] + bb.z; r.w = acc[i][3] + bb.w;
        *(float4*)(P + (size_t)(v0 + ty * 4 + i) * K_N + j0 + tx * 4) = r;
    }
}

// ---- phase 3: 2-WG-per-chain k-split RNN, weights fully on-chip ----
// 96 blocks x 512 threads; block = (g, dir, ws). WG ws owns k-rows
// [256*ws, 256*ws+256): 512 KB of Wh = 128 KB LDS (rows 0..7 per thread)
// + 192 VGPR (rows 8..31 per thread). ZERO weight streaming per step
// (R2/R3 lesson: streaming is TCP-bound at >=4.5us/step).
// Thread (q = tid>>6 = wave, c = tid&63) owns cols 8c..8c+7 over its
// 32-row k-slice; per row 2 float4 of Wh. h broadcast via wave-uniform
// LDS float4 reads. Each WG produces a 512-col partial over its k-half;
// the two halves are exchanged through the LLC with the R0-proven
// relaxed-agent-atomic + release/acquire-flag protocol (2 KB each way),
// then BOTH WGs redundantly finish tanh -> full h (no h exchange needed).
__global__ __attribute__((amdgpu_flat_work_group_size(512, 512), amdgpu_waves_per_eu(2, 2)))
void rnn_pair(const float* __restrict__ P, const float* __restrict__ Wh,
              const int* __restrict__ rows, float* __restrict__ h_buf,
              int* __restrict__ flags, float* __restrict__ out) {

    __shared__ __align__(16) float  lds_h[K_N];          // 2 KB
    __shared__ __align__(16) float4 Wlds[16 * 512];      // 128 KB: [j][tid]
    __shared__ __align__(16) float  pr[2][8][256];       // 16 KB, 16B-stride writes

    const int tid = threadIdx.x;
    const int q   = tid >> 6;          // wave id = k-subgroup (32 rows)
    const int c   = tid & 63;          // col group: cols 8c..8c+7
    const int cluster = blockIdx.x >> 1;
    const int ws  = blockIdx.x & 1;    // k-half
    const int g   = cluster >> 1;
    const int dir = cluster & 1;

    const float4* __restrict__ Wh4 = (const float4*)Wh;
    const int kbase = (ws << 8) + (q << 5);                    // 256*ws + 32*q
    const float4* __restrict__ wb = Wh4 + (size_t)kbase * 128 + 2 * c;

    // register tier: rows 8..31 (48 float4 = 192 VGPR)
    float4 Wreg[48];
#pragma unroll
    for (int r = 8; r < 32; r++) {
        Wreg[(r - 8) * 2 + 0] = wb[(size_t)r * 128 + 0];
        Wreg[(r - 8) * 2 + 1] = wb[(size_t)r * 128 + 1];
    }
    // LDS tier: rows 0..7 (each wave reads back only its own [*][tid] slots)
#pragma unroll
    for (int r = 0; r < 8; r++) {
        Wlds[(2 * r + 0) * 512 + tid] = wb[(size_t)r * 128 + 0];
        Wlds[(2 * r + 1) * 512 + tid] = wb[(size_t)r * 128 + 1];
    }
    lds_h[tid] = 0.f;

    const int* __restrict__ myrows = rows + g * T_LEN;
    int t0 = (dir == 0) ? 0 : (T_LEN - 2);
    float xv = P[(size_t)myrows[t0] * K_N + tid];
    int t1 = (dir == 0) ? 1 : (T_LEN - 3);
    int rnxt = myrows[t1];

    int* myflag = flags + cluster * 2 + ws;
    int* pflag  = flags + cluster * 2 + (ws ^ 1);
    float* hbme = h_buf + ((size_t)cluster * 2 + ws) * 1024;        // 2 ping-pong x 512
    float* hbpt = h_buf + ((size_t)cluster * 2 + (ws ^ 1)) * 1024;

    const size_t outbase = (size_t)g * 1024 + (size_t)dir * 512 + tid;
    float h_prev = 0.f;
    size_t prev_addr = 0;

    __syncthreads();

    for (int s = 0; s < T_LEN; s++) {
        // staggered out store (ws0 only): drains under the FMA phase
        if (ws == 0 && s > 0) __builtin_nontemporal_store(h_prev, &out[prev_addr]);
        // x prefetch for s+1; row index for s+2
        float xv_next = 0.f;
        if (s + 1 < T_LEN) xv_next = P[(size_t)rnxt * K_N + tid];
        if (s + 2 < T_LEN) {
            int sn = s + 2;
            int tn = (dir == 0) ? sn : ((sn == T_LEN - 1) ? (T_LEN - 1) : (T_LEN - 2 - sn));
            rnxt = myrows[tn];
        }

        // ---- FMA phase: 32 rows x 8 cols, weights from regs/LDS only ----
        const float4* __restrict__ h4 = (const float4*)lds_h;
        const int hb4 = (ws << 6) + (q << 3);          // wave-uniform h base (f4)
        float4 acc0 = {0, 0, 0, 0}, acc1 = {0, 0, 0, 0};
#pragma unroll
        for (int r8 = 0; r8 < 8; r8++) {
            float4 hv = h4[hb4 + r8];                  // uniform -> broadcast
#pragma unroll
            for (int e = 0; e < 4; e++) {
                float hs = (e == 0) ? hv.x : (e == 1) ? hv.y : (e == 2) ? hv.z : hv.w;
                float4 w0, w1;
                if (r8 < 2) {                          // LDS rows 0..7
                    int j = (4 * r8 + e) * 2;
                    w0 = Wlds[(j + 0) * 512 + tid];
                    w1 = Wlds[(j + 1) * 512 + tid];
                } else {                               // reg rows 8..31
                    int m = (4 * r8 + e - 8) * 2;
                    w0 = Wreg[m]; w1 = Wreg[m + 1];
                }
                acc0.x += hs * w0.x; acc0.y += hs * w0.y; acc0.z += hs * w0.z; acc0.w += hs * w0.w;
                acc1.x += hs * w1.x; acc1.y += hs * w1.y; acc1.z += hs * w1.z; acc1.w += hs * w1.w;
            }
        }
        // per-wave partials: 16B-stride float4 writes, conflict-free
        *(float4*)&pr[0][q][4 * c] = acc0;             // cols 8c..8c+3
        *(float4*)&pr[1][q][4 * c] = acc1;             // cols 8c+4..8c+7
        __syncthreads();                               // A

        // ---- reduce 8 k-subgroups for own column j = tid ----
        {
            const int cc = tid >> 3, w = tid & 7;
            const int pl = w >> 2, e = w & 3;
            const float* base = &pr[pl][0][4 * cc + e];
            float p0 = base[0 * 256], p1 = base[1 * 256], p2 = base[2 * 256], p3 = base[3 * 256];
            float p4 = base[4 * 256], p5 = base[5 * 256], p6 = base[6 * 256], p7 = base[7 * 256];
            float own = ((p0 + p1) + (p2 + p3)) + ((p4 + p5) + (p6 + p7));

            STORE_RLX(&hbme[(s & 1) * 512 + tid], own);   // sc1: straight to LLC
            __syncthreads();                              // B: drains the LLC store
            if (tid == 0) {
                __hip_atomic_store(myflag, s + 1, __ATOMIC_RELEASE, __HIP_MEMORY_SCOPE_AGENT);
                while (LOAD_RLX(pflag) < s + 1) { }
            }
            __builtin_amdgcn_fence(__ATOMIC_ACQUIRE, "workgroup");
            __syncthreads();                              // C
            float pv = LOAD_RLX(&hbpt[(s & 1) * 512 + tid]);

            float z = xv + (own + pv);
            z = fminf(15.f, fmaxf(-15.f, z));
            float e2 = __expf(2.f * z);
            float h1 = 1.f - 2.f / (e2 + 1.f);            // tanh(z)
            xv = xv_next;

            int tphys = (dir == 0) ? s : ((s == T_LEN - 1) ? (T_LEN - 1) : (T_LEN - 2 - s));
            prev_addr = (size_t)tphys * (G_N * 1024) + outbase;
            h_prev = h1;
            if (s == T_LEN - 1) break;
            lds_h[tid] = h1;                              // all lds_h reads done pre-A
        }
        __syncthreads();                                  // D: h_s visible next step
    }
    if (ws == 0) {
        __builtin_nontemporal_store(h_prev, &out[prev_addr]);
        __builtin_nontemporal_store(h_prev, &out[(size_t)T_LEN * (G_N * 1024) + outbase]);
    }
}

extern "C" void kernel_launch(void* const* d_in, const int* in_sizes, int n_in,
                              void* d_out, int out_size, void* d_ws, size_t ws_size,
                              hipStream_t stream) {
    const float* seq   = (const float*)d_in[0];
    const int*   perms = (const int*)d_in[1];
    const float* We    = (const float*)d_in[2];
    const float* Wx    = (const float*)d_in[3];
    const float* Wh    = (const float*)d_in[4];
    const float* b     = (const float*)d_in[5];
    float* out = (float*)d_out;
    char* ws = (char*)d_ws;

    int*   flags  = (int*)(ws + FLAGS_OFF);
    int*   tokens = (int*)(ws + TOK_OFF);
    int*   rows   = (int*)(ws + ROWS_OFF);
    float* hbuf   = (float*)(ws + HBUF_OFF);
    float* P      = (float*)(ws + P_OFF);

    (void)hipMemsetAsync(flags, 0, NCL * 2 * sizeof(int), stream);
    tok_kernel<<<512, 256, 0, stream>>>(seq, tokens);
    rows_kernel<<<(G_N * T_LEN + 255) / 256, 256, 0, stream>>>(tokens, perms, rows);
    pgemm_kernel<<<256, 256, 0, stream>>>(We, Wx, b, P);
    rnn_pair<<<NBLK, 512, 0, stream>>>(P, Wh, rows, hbuf, flags, out);
}